// Round 6
// baseline (164.496 us; speedup 1.0000x reference)
//
#include <hip/hip_runtime.h>
#include <hip/hip_bf16.h>

// LengthRegulator: x[B,T,D] f32, duration[B,T] i32, src_lens[B] i32, max_len=4096.
// out = gather-expand rows of x per cumulative duration; frames >= tgt_len are 0.
// d_out layout (all float32): out[B*L*D] then tgt_len[B] (as float).
//
// Two-kernel design:
//   A: per-batch masked cumsum (32 blocks) -> ws_cum[B][T], ws_tlen[B], tgt_len tail.
//   B: expand (2048 blocks, 64 frames each). Blocks fully past tlen stream zeros
//      (no LDS/barrier/search). Valid blocks: cum -> LDS, 64 parallel searches,
//      then fully-coalesced 1KB-row copies (64 lanes x float4 per row).

#define BB 32
#define TT 512
#define DD 256
#define LL 4096
#define D4 (DD / 4)    // 64 float4 per row
#define FPB 64         // frames per block (kernel B)
#define BPB (LL / FPB) // blocks per batch = 64

__global__ __launch_bounds__(256) void lr_scan_kernel(
    const int* __restrict__ duration,
    const int* __restrict__ src_lens,
    int*       __restrict__ ws_cum,   // [BB*TT]
    int*       __restrict__ ws_tlen,  // [BB]
    float*     __restrict__ out_f)
{
    __shared__ int sc[2][TT];
    const int b   = blockIdx.x;
    const int tid = threadIdx.x;
    const int slen = src_lens[b];

    for (int i = tid; i < TT; i += 256)
        sc[0][i] = (i < slen) ? duration[b * TT + i] : 0;
    __syncthreads();

    int src = 0;
    for (int off = 1; off < TT; off <<= 1) {
        for (int i = tid; i < TT; i += 256) {
            int v = sc[src][i];
            if (i >= off) v += sc[src][i - off];
            sc[src ^ 1][i] = v;
        }
        __syncthreads();
        src ^= 1;
    }

    for (int i = tid; i < TT; i += 256)
        ws_cum[b * TT + i] = sc[src][i];
    if (tid == 0) {
        const int tlen = sc[src][TT - 1];
        ws_tlen[b] = tlen;
        out_f[(size_t)BB * LL * DD + b] = (float)tlen;  // tgt_len output (as f32)
    }
}

__global__ __launch_bounds__(256) void lr_expand_kernel(
    const float4* __restrict__ x,
    const int*    __restrict__ ws_cum,
    const int*    __restrict__ ws_tlen,
    float4*       __restrict__ out4)
{
    const int b     = blockIdx.x / BPB;
    const int chunk = blockIdx.x % BPB;
    const int tid   = threadIdx.x;
    const int lane  = tid & 63;
    const int wave  = tid >> 6;
    const int j0    = chunk * FPB;
    const int tlen  = ws_tlen[b];
    const float4 zero = make_float4(0.f, 0.f, 0.f, 0.f);

    if (j0 >= tlen) {
        // Pure-zero block (~78% of blocks on average): stream 64KB of zeros.
        #pragma unroll 4
        for (int f = wave; f < FPB; f += 4)
            out4[((size_t)b * LL + j0 + f) * D4 + lane] = zero;
        return;
    }

    __shared__ int cum[TT];
    __shared__ int idxs[FPB];

    for (int i = tid; i < TT; i += 256)
        cum[i] = ws_cum[b * TT + i];
    __syncthreads();

    // 64 independent searches, one thread per frame (parallel, not wave-serial).
    if (tid < FPB) {
        const int j = j0 + tid;
        int idx = -1;
        if (j < tlen) {
            int lo = 0, hi = TT;
            while (lo < hi) {
                const int mid = (lo + hi) >> 1;
                if (cum[mid] > j) hi = mid; else lo = mid + 1;
            }
            idx = lo < (TT - 1) ? lo : (TT - 1);
        }
        idxs[tid] = idx;
    }
    __syncthreads();

    // Each wave copies one full 1KB row per iteration (64 lanes x float4).
    #pragma unroll 4
    for (int f = wave; f < FPB; f += 4) {
        const int idx = idxs[f];  // LDS broadcast
        const float4 v = (idx >= 0) ? x[((size_t)b * TT + idx) * D4 + lane] : zero;
        out4[((size_t)b * LL + j0 + f) * D4 + lane] = v;
    }
}

extern "C" void kernel_launch(void* const* d_in, const int* in_sizes, int n_in,
                              void* d_out, int out_size, void* d_ws, size_t ws_size,
                              hipStream_t stream) {
    const float4* x        = (const float4*)d_in[0];
    const int*    duration = (const int*)d_in[1];
    const int*    src_lens = (const int*)d_in[2];
    float*        out_f    = (float*)d_out;

    int* ws_cum  = (int*)d_ws;           // BB*TT ints = 64 KB
    int* ws_tlen = ws_cum + BB * TT;     // BB ints

    lr_scan_kernel<<<dim3(BB), dim3(256), 0, stream>>>(duration, src_lens, ws_cum, ws_tlen, out_f);
    lr_expand_kernel<<<dim3(BB * BPB), dim3(256), 0, stream>>>(x, ws_cum, ws_tlen, (float4*)out_f);
}